// Round 1
// baseline (135.948 us; speedup 1.0000x reference)
//
#include <hip/hip_runtime.h>

#define N_TOK 8192
#define N_CH  64
#define N_CR  32

typedef _Float16 f16x8 __attribute__((ext_vector_type(8)));
typedef _Float16 f16x4 __attribute__((ext_vector_type(4)));
typedef float    f32x4 __attribute__((ext_vector_type(4)));

__device__ __forceinline__ f32x4 mfma16(f16x8 a, f16x8 b, f32x4 c) {
  return __builtin_amdgcn_mfma_f32_16x16x32_f16(a, b, c, 0, 0, 0);
}

// QSCALE^2 = log2(e)/sqrt(32); fold softmax scale + ln->log2 into q so
// s2[n,m] = qe_n . qe_m is directly the exp2 exponent.
#define QSCALE 0.50500977f

// ---------------------------------------------------------------------------
// Kernel A: qe[n][32] = fp16((W x + bias) * QSCALE); vh = fp16(x)
// blocks 0..1023: one thread per (n,o). blocks 1024..1279: vh convert.
// ---------------------------------------------------------------------------
__global__ __launch_bounds__(256) void prep_kernel(
    const float* __restrict__ x, const float* __restrict__ W,
    const float* __restrict__ bias, _Float16* __restrict__ qe,
    _Float16* __restrict__ vh) {
  int blk = blockIdx.x, t = threadIdx.x;
  if (blk < 1024) {
    __shared__ float Wl[32 * 65];  // pad 65: avoids 32-way bank conflict
    for (int i = t; i < 2048; i += 256) Wl[(i >> 6) * 65 + (i & 63)] = W[i];
    __syncthreads();
    int g = blk * 256 + t;
    int o = g & 31, n = g >> 5;
    float acc = bias[o];
#pragma unroll
    for (int c = 0; c < 64; ++c)
      acc = fmaf(Wl[o * 65 + c], x[c * N_TOK + n], acc);
    qe[n * 32 + o] = (_Float16)(acc * QSCALE);
  } else {
    int base = (blk - 1024) * 2048 + t;
#pragma unroll
    for (int j = 0; j < 8; ++j) {
      int i = base + j * 256;
      vh[i] = (_Float16)x[i];
    }
  }
}

// ---------------------------------------------------------------------------
// Kernel B (pass 1): Bn[n] = log2( sum_m exp2(qe_n . qe_m) )
// 512 blocks x 256 thr; block = 16 rows; 4 waves split the 8192 m-columns.
// ---------------------------------------------------------------------------
__global__ __launch_bounds__(256) void pass1_kernel(
    const _Float16* __restrict__ qe, float* __restrict__ Bn) {
  __shared__ float Lp[64];
  int t = threadIdx.x;
  int w = t >> 6, lane = t & 63, quad = lane >> 4, l15 = lane & 15;
  int n0 = blockIdx.x * 16;
  // A frag: rows n0..n0+15, lane holds A[m=l15][k=quad*8+j]
  f16x8 af = *(const f16x8*)(qe + (n0 + l15) * 32 + quad * 8);
  f32x4 sums = {0.f, 0.f, 0.f, 0.f};
  for (int mt = 0; mt < 128; ++mt) {
    int m0 = w * 2048 + mt * 16;
    f16x8 bf = *(const f16x8*)(qe + (m0 + l15) * 32 + quad * 8);
    f32x4 zero = {0.f, 0.f, 0.f, 0.f};
    f32x4 s = mfma16(af, bf, zero);  // s[r]: row n=quad*4+r, col m=l15
#pragma unroll
    for (int r = 0; r < 4; ++r) sums[r] += __builtin_amdgcn_exp2f(s[r]);
  }
  // reduce over the 16 columns (lanes within each quad)
#pragma unroll
  for (int r = 0; r < 4; ++r) {
#pragma unroll
    for (int mask = 1; mask < 16; mask <<= 1)
      sums[r] += __shfl_xor(sums[r], mask, 64);
  }
  if (l15 == 0) *(f32x4*)&Lp[w * 16 + quad * 4] = sums;
  __syncthreads();
  if (t < 16) {
    float L = Lp[t] + Lp[16 + t] + Lp[32 + t] + Lp[48 + t];
    Bn[n0 + t] = __builtin_amdgcn_logf(L);  // log2
  }
}

// ---------------------------------------------------------------------------
// Kernel C (pass 2): out[c,m] = sum_n vh[c,n] * exp2(qe_n.qe_m - Bn[n]) + x
// 256 blocks x 512 thr (8 waves). Block covers BM=32 cols, all 64 c.
// Waves split n 8 ways (1024 each); partials combined in LDS.
// ---------------------------------------------------------------------------
__global__ __launch_bounds__(512) void pass2_kernel(
    const _Float16* __restrict__ qe, const _Float16* __restrict__ vh,
    const float* __restrict__ Bn, const float* __restrict__ x,
    float* __restrict__ out) {
  __shared__ _Float16 Pt[8 * 1280];  // per-wave P^T tile: [32 m][stride 40] halves
  __shared__ float Ot[4 * 64 * 33];  // partial-out combine: [4][64 c][33]
  int t = threadIdx.x;
  int w = t >> 6, lane = t & 63, quad = lane >> 4, l15 = lane & 15;
  int m0 = blockIdx.x * 32;
  _Float16* myP = Pt + w * 1280;

  // B frags for the S matmul: cols m0..m0+31 (fixed for whole kernel)
  f16x8 bm0 = *(const f16x8*)(qe + (m0 + l15) * 32 + quad * 8);
  f16x8 bm1 = *(const f16x8*)(qe + (m0 + 16 + l15) * 32 + quad * 8);

  f32x4 acc[4][2];
#pragma unroll
  for (int ct = 0; ct < 4; ++ct)
#pragma unroll
    for (int mt = 0; mt < 2; ++mt) acc[ct][mt] = f32x4{0.f, 0.f, 0.f, 0.f};

  for (int ch = 0; ch < 32; ++ch) {
    int nb = w * 1024 + ch * 32;
    f16x8 an[2];
    an[0] = *(const f16x8*)(qe + (nb + l15) * 32 + quad * 8);
    an[1] = *(const f16x8*)(qe + (nb + 16 + l15) * 32 + quad * 8);
    f32x4 Bq[2];
    Bq[0] = *(const f32x4*)(Bn + nb + quad * 4);
    Bq[1] = *(const f32x4*)(Bn + nb + 16 + quad * 4);
#pragma unroll
    for (int nt = 0; nt < 2; ++nt) {
      f16x8 a = an[nt];
#pragma unroll
      for (int mt = 0; mt < 2; ++mt) {
        f32x4 zero = {0.f, 0.f, 0.f, 0.f};
        f32x4 s = mfma16(a, (mt == 0) ? bm0 : bm1, zero);
        f16x4 p;
#pragma unroll
        for (int r = 0; r < 4; ++r)
          p[r] = (_Float16)__builtin_amdgcn_exp2f(s[r] - Bq[nt][r]);
        // C layout: row n_local = quad*4+r, col m_local = l15.
        // Store transposed: Pt[m_local][n_local], n contiguous.
        *(f16x4*)(myP + (mt * 16 + l15) * 40 + nt * 16 + quad * 4) = p;
      }
    }
    __syncthreads();
    // Read back as B operand for PV: B[k=n=quad*8+i][col=m=l15]
    f16x8 bp0 = *(const f16x8*)(myP + l15 * 40 + quad * 8);
    f16x8 bp1 = *(const f16x8*)(myP + (16 + l15) * 40 + quad * 8);
#pragma unroll
    for (int ct = 0; ct < 4; ++ct) {
      f16x8 av = *(const f16x8*)(vh + (ct * 16 + l15) * N_TOK + nb + quad * 8);
      acc[ct][0] = mfma16(av, bp0, acc[ct][0]);
      acc[ct][1] = mfma16(av, bp1, acc[ct][1]);
    }
    __syncthreads();  // WAR guard before next chunk overwrites Pt
  }

  // Combine partials across the 8 n-segments.
  if (w < 4) {
#pragma unroll
    for (int ct = 0; ct < 4; ++ct)
#pragma unroll
      for (int mt = 0; mt < 2; ++mt)
#pragma unroll
        for (int r = 0; r < 4; ++r)
          Ot[(w * 64 + ct * 16 + quad * 4 + r) * 33 + mt * 16 + l15] =
              acc[ct][mt][r];
  }
  __syncthreads();
  if (w >= 4) {
#pragma unroll
    for (int ct = 0; ct < 4; ++ct)
#pragma unroll
      for (int mt = 0; mt < 2; ++mt)
#pragma unroll
        for (int r = 0; r < 4; ++r)
          Ot[((w - 4) * 64 + ct * 16 + quad * 4 + r) * 33 + mt * 16 + l15] +=
              acc[ct][mt][r];
  }
  __syncthreads();
  int m = t & 31, cb = t >> 5;  // cb in 0..15
  for (int cc = cb; cc < 64; cc += 16) {
    float v = 0.f;
#pragma unroll
    for (int ww = 0; ww < 4; ++ww) v += Ot[(ww * 64 + cc) * 33 + m];
    out[cc * N_TOK + m0 + m] = v + x[cc * N_TOK + m0 + m];
  }
}

// ---------------------------------------------------------------------------
extern "C" void kernel_launch(void* const* d_in, const int* in_sizes, int n_in,
                              void* d_out, int out_size, void* d_ws,
                              size_t ws_size, hipStream_t stream) {
  const float* x = (const float*)d_in[0];     // [64][8192]
  const float* W = (const float*)d_in[1];     // [32][64]
  const float* bias = (const float*)d_in[2];  // [32]
  float* out = (float*)d_out;                 // [64][8192]

  char* ws = (char*)d_ws;
  _Float16* qe = (_Float16*)ws;                         // 8192*32*2 = 512 KB
  _Float16* vh = (_Float16*)(ws + 524288);              // 64*8192*2 = 1 MB
  float* Bn = (float*)(ws + 524288 + 1048576);          // 8192*4 = 32 KB

  prep_kernel<<<1280, 256, 0, stream>>>(x, W, bias, qe, vh);
  pass1_kernel<<<512, 256, 0, stream>>>(qe, Bn);
  pass2_kernel<<<256, 512, 0, stream>>>(qe, vh, Bn, x, out);
}

// Round 2
// 113.899 us; speedup vs baseline: 1.1936x; 1.1936x over previous
//
#include <hip/hip_runtime.h>

#define N_TOK 8192

typedef _Float16 f16x8 __attribute__((ext_vector_type(8)));
typedef _Float16 f16x4 __attribute__((ext_vector_type(4)));
typedef float    f32x4 __attribute__((ext_vector_type(4)));

__device__ __forceinline__ f32x4 mfma16(f16x8 a, f16x8 b, f32x4 c) {
  return __builtin_amdgcn_mfma_f32_16x16x32_f16(a, b, c, 0, 0, 0);
}

// QSCALE^2 = log2(e)/sqrt(32); fold softmax scale + ln->log2 into q so
// s2[n,m] = qe_n . qe_m is directly the exp2 exponent.
#define QSCALE 0.50500977f

// ---------------------------------------------------------------------------
// Kernel A: qe[n][32] = fp16((W x + bias) * QSCALE); vh = fp16(x)
// blocks 0..1023: one thread per (n,o), 2-chain ILP over c.
// blocks 1024..1535: vh convert, float4-vectorized.
// ---------------------------------------------------------------------------
__global__ __launch_bounds__(256) void prep_kernel(
    const float* __restrict__ x, const float* __restrict__ W,
    const float* __restrict__ bias, _Float16* __restrict__ qe,
    _Float16* __restrict__ vh) {
  int blk = blockIdx.x, t = threadIdx.x;
  if (blk < 1024) {
    __shared__ float Wl[32 * 65];  // pad 65: lane-distinct banks
    for (int i = t; i < 2048; i += 256) Wl[(i >> 6) * 65 + (i & 63)] = W[i];
    __syncthreads();
    int g = blk * 256 + t;
    int o = g & 31, n = g >> 5;
    float acc0 = bias[o], acc1 = 0.f;
#pragma unroll
    for (int c = 0; c < 32; ++c) {
      acc0 = fmaf(Wl[o * 65 + c], x[c * N_TOK + n], acc0);
      acc1 = fmaf(Wl[o * 65 + 32 + c], x[(32 + c) * N_TOK + n], acc1);
    }
    qe[n * 32 + o] = (_Float16)((acc0 + acc1) * QSCALE);
  } else {
    int i4 = (blk - 1024) * 256 + t;  // float4 index, 512 blocks cover 512K elts
    f32x4 v = ((const f32x4*)x)[i4];
    f16x4 h;
#pragma unroll
    for (int j = 0; j < 4; ++j) h[j] = (_Float16)v[j];
    *(f16x4*)(vh + i4 * 4) = h;
  }
}

// ---------------------------------------------------------------------------
// Kernel B (pass 1): Bn[n] = log2( sum_m exp2(qe_n . qe_m) )
// 256 blocks x 512 thr; block = 32 rows (2 A-frags -> 2 indep MFMA chains);
// 8 waves split the 8192 m-columns (1024 each).
// ---------------------------------------------------------------------------
__global__ __launch_bounds__(512) void pass1_kernel(
    const _Float16* __restrict__ qe, float* __restrict__ Bn) {
  __shared__ float Lp[8][32];
  int t = threadIdx.x;
  int w = t >> 6, lane = t & 63, quad = lane >> 4, l15 = lane & 15;
  int n0 = blockIdx.x * 32;
  f16x8 af0 = *(const f16x8*)(qe + (n0 + l15) * 32 + quad * 8);
  f16x8 af1 = *(const f16x8*)(qe + (n0 + 16 + l15) * 32 + quad * 8);
  f32x4 sums0 = {0.f, 0.f, 0.f, 0.f}, sums1 = {0.f, 0.f, 0.f, 0.f};
  for (int mt = 0; mt < 64; ++mt) {
    int m0 = w * 1024 + mt * 16;
    f16x8 bf = *(const f16x8*)(qe + (m0 + l15) * 32 + quad * 8);
    f32x4 zero = {0.f, 0.f, 0.f, 0.f};
    f32x4 s0 = mfma16(af0, bf, zero);  // rows n0+quad*4+r, col m0+l15
    f32x4 s1 = mfma16(af1, bf, zero);  // rows n0+16+quad*4+r
#pragma unroll
    for (int r = 0; r < 4; ++r) {
      sums0[r] += __builtin_amdgcn_exp2f(s0[r]);
      sums1[r] += __builtin_amdgcn_exp2f(s1[r]);
    }
  }
  // reduce across the 16 m-columns (l15 bits = lane bits 0..3)
#pragma unroll
  for (int r = 0; r < 4; ++r) {
#pragma unroll
    for (int mask = 1; mask < 16; mask <<= 1) {
      sums0[r] += __shfl_xor(sums0[r], mask, 64);
      sums1[r] += __shfl_xor(sums1[r], mask, 64);
    }
  }
  if (l15 == 0) {
    *(f32x4*)&Lp[w][quad * 4] = sums0;
    *(f32x4*)&Lp[w][16 + quad * 4] = sums1;
  }
  __syncthreads();
  if (t < 32) {
    float L = 0.f;
#pragma unroll
    for (int ww = 0; ww < 8; ++ww) L += Lp[ww][t];
    Bn[n0 + t] = __builtin_amdgcn_logf(L);  // v_log_f32 = log2
  }
}

// ---------------------------------------------------------------------------
// Kernel C (pass 2): out[c,m] = sum_n vh[c,n] * exp2(qe_n.qe_m - Bn[n]) + x
// 256 blocks x 1024 thr (16 waves). Block = 32 m-cols, all 64 c.
// Waves split n 16 ways (512 each). NO barriers in the chunk loop: the P
// transpose LDS region is wave-private; in-order DS + lgkmcnt suffices.
// ---------------------------------------------------------------------------
__global__ __launch_bounds__(1024) void pass2_kernel(
    const _Float16* __restrict__ qe, const _Float16* __restrict__ vh,
    const float* __restrict__ Bn, const float* __restrict__ x,
    float* __restrict__ out) {
  __shared__ _Float16 Pt[16 * 1280];  // per-wave P^T tile: [32 m][stride 40]
  __shared__ float Ot[8 * 64 * 33];   // combine: [8 sets][64 c][33]
  int t = threadIdx.x;
  int w = t >> 6, lane = t & 63, quad = lane >> 4, l15 = lane & 15;
  int m0 = blockIdx.x * 32;
  _Float16* myP = Pt + w * 1280;

  // B frags for the S matmul: cols m0..m0+31 (fixed for whole kernel)
  f16x8 bm0 = *(const f16x8*)(qe + (m0 + l15) * 32 + quad * 8);
  f16x8 bm1 = *(const f16x8*)(qe + (m0 + 16 + l15) * 32 + quad * 8);

  f32x4 acc[4][2];
#pragma unroll
  for (int ct = 0; ct < 4; ++ct)
#pragma unroll
    for (int mt = 0; mt < 2; ++mt) acc[ct][mt] = f32x4{0.f, 0.f, 0.f, 0.f};

  for (int ch = 0; ch < 16; ++ch) {
    int nb = w * 512 + ch * 32;
    f16x8 an[2];
    an[0] = *(const f16x8*)(qe + (nb + l15) * 32 + quad * 8);
    an[1] = *(const f16x8*)(qe + (nb + 16 + l15) * 32 + quad * 8);
    f32x4 Bq[2];
    Bq[0] = *(const f32x4*)(Bn + nb + quad * 4);
    Bq[1] = *(const f32x4*)(Bn + nb + 16 + quad * 4);
    // WAR guard: previous iteration's ds_reads must complete before we
    // overwrite myP (in-order DS per wave; asm blocks compiler reordering).
    __asm__ volatile("s_waitcnt lgkmcnt(0)" ::: "memory");
#pragma unroll
    for (int nt = 0; nt < 2; ++nt) {
      f16x8 a = an[nt];
#pragma unroll
      for (int mt = 0; mt < 2; ++mt) {
        f32x4 zero = {0.f, 0.f, 0.f, 0.f};
        f32x4 s = mfma16(a, (mt == 0) ? bm0 : bm1, zero);
        f16x4 p;
#pragma unroll
        for (int r = 0; r < 4; ++r)
          p[r] = (_Float16)__builtin_amdgcn_exp2f(s[r] - Bq[nt][r]);
        // C layout: row n_local = nt*16+quad*4+r, col m_local = mt*16+l15.
        // Store transposed: Pt[m_local][n_local], n contiguous.
        *(f16x4*)(myP + (mt * 16 + l15) * 40 + nt * 16 + quad * 4) = p;
      }
    }
    // RAW guard: writes above visible to whole wave before cross-lane read.
    __asm__ volatile("s_waitcnt lgkmcnt(0)" ::: "memory");
    // Read back as B operand for PV: B[k=n=quad*8+i][col=m=l15]
    f16x8 bp0 = *(const f16x8*)(myP + l15 * 40 + quad * 8);
    f16x8 bp1 = *(const f16x8*)(myP + (16 + l15) * 40 + quad * 8);
#pragma unroll
    for (int ct = 0; ct < 4; ++ct) {
      f16x8 av = *(const f16x8*)(vh + (ct * 16 + l15) * N_TOK + nb + quad * 8);
      acc[ct][0] = mfma16(av, bp0, acc[ct][0]);
      acc[ct][1] = mfma16(av, bp1, acc[ct][1]);
    }
  }

  // Combine partials across the 16 n-segments (staged: 16 -> 8 -> 1).
  if (w < 8) {
#pragma unroll
    for (int ct = 0; ct < 4; ++ct)
#pragma unroll
      for (int mt = 0; mt < 2; ++mt)
#pragma unroll
        for (int r = 0; r < 4; ++r)
          Ot[(w * 64 + ct * 16 + quad * 4 + r) * 33 + mt * 16 + l15] =
              acc[ct][mt][r];
  }
  __syncthreads();
  if (w >= 8) {
#pragma unroll
    for (int ct = 0; ct < 4; ++ct)
#pragma unroll
      for (int mt = 0; mt < 2; ++mt)
#pragma unroll
        for (int r = 0; r < 4; ++r)
          Ot[((w - 8) * 64 + ct * 16 + quad * 4 + r) * 33 + mt * 16 + l15] +=
              acc[ct][mt][r];
  }
  __syncthreads();
  // 2048 outputs, 1024 threads -> 2 each; m consecutive across lanes.
  for (int idx = t; idx < 2048; idx += 1024) {
    int cc = idx >> 5, m = idx & 31;
    float v = 0.f;
#pragma unroll
    for (int s = 0; s < 8; ++s) v += Ot[(s * 64 + cc) * 33 + m];
    out[cc * N_TOK + m0 + m] = v + x[cc * N_TOK + m0 + m];
  }
}

// ---------------------------------------------------------------------------
extern "C" void kernel_launch(void* const* d_in, const int* in_sizes, int n_in,
                              void* d_out, int out_size, void* d_ws,
                              size_t ws_size, hipStream_t stream) {
  const float* x = (const float*)d_in[0];     // [64][8192]
  const float* W = (const float*)d_in[1];     // [32][64]
  const float* bias = (const float*)d_in[2];  // [32]
  float* out = (float*)d_out;                 // [64][8192]

  char* ws = (char*)d_ws;
  _Float16* qe = (_Float16*)ws;                 // 8192*32*2 = 512 KB
  _Float16* vh = (_Float16*)(ws + 524288);      // 64*8192*2 = 1 MB
  float* Bn = (float*)(ws + 524288 + 1048576);  // 8192*4 = 32 KB

  prep_kernel<<<1536, 256, 0, stream>>>(x, W, bias, qe, vh);
  pass1_kernel<<<256, 512, 0, stream>>>(qe, Bn);
  pass2_kernel<<<256, 1024, 0, stream>>>(qe, vh, Bn, x, out);
}